// Round 2
// 189.994 us; speedup vs baseline: 1.0033x; 1.0033x over previous
//
#include <hip/hip_runtime.h>

// Problem constants (static shapes from reference)
#define B 64
#define C 2048
#define H 24
#define W 8
#define HW (H * W)            // 192 spatial positions per (b,c)
#define HW4 (HW / 4)          // 48 float4 per channel row
#define CHUNKS 16             // channel chunks per batch for parallelism
#define CPC (C / CHUNKS)      // 128 channels per chunk
#define RH 8                  // round(0.33 * 24) = 8 rows zeroed
#define CHW4 ((C * HW) / 4)   // float4s per batch = 98304

typedef float f32x4 __attribute__((ext_vector_type(4)));

// ---------------------------------------------------------------------------
// Kernel 1: partial sum of squares over a channel chunk, float4 loads.
// grid = B*CHUNKS blocks, block = 192 threads (3 waves).
// Thread t: q = t % 48 (float4 position), g = t / 48 (channel subgroup 0..3).
// Per j-iteration the block reads 4 consecutive channel rows = 3072 B
// contiguous, 16 B/lane (global_load_dwordx4, fully coalesced).
// LDS reduce across the 4 channel subgroups, then one float4 partial store.
// ---------------------------------------------------------------------------
__global__ __launch_bounds__(192) void k_ss(const f32x4* __restrict__ x4,
                                            f32x4* __restrict__ partial4) {
    const int blk = blockIdx.x;
    const int b = blk / CHUNKS;
    const int chunk = blk % CHUNKS;
    const int t = threadIdx.x;
    const int q = t % HW4;   // float4 position within the 192-float spatial row
    const int g = t / HW4;   // channel subgroup (0..3)

    // channel = chunk*CPC + j*4 + g
    const f32x4* p = x4 + (size_t)(b * C + chunk * CPC + g) * HW4 + q;
    f32x4 acc = {0.f, 0.f, 0.f, 0.f};
    #pragma unroll
    for (int j = 0; j < CPC / 4; ++j) {           // 32 iterations
        const f32x4 v = p[(size_t)j * 4 * HW4];   // stride = 4 channel rows
        acc += v * v;                              // elementwise fma
    }

    __shared__ f32x4 sm[4][HW4];  // 3 KB; linear index == t, conflict-free
    sm[g][q] = acc;
    __syncthreads();

    if (t < HW4) {
        const f32x4 a0 = sm[0][t], a1 = sm[1][t], a2 = sm[2][t], a3 = sm[3][t];
        partial4[(size_t)blk * HW4 + t] = (a0 + a1) + (a2 + a3);
    }
}

// ---------------------------------------------------------------------------
// Kernel 2: reduce partials -> per-row max -> rank rows -> mask.
// grid = B blocks, block = 64 threads (ONE wave: minimal latency).
// Lane t < 48 owns float4 position t; lanes 2h / 2h+1 hold the two float4
// halves of row h (W=8). All 16 chunk loads are independent (one memory
// round trip). Row max via shfl_xor(1). Tie-break (o == my && h > t)
// matches stable ascending argsort taking the LAST rh entries.
// ---------------------------------------------------------------------------
__global__ __launch_bounds__(64) void k_mask(const f32x4* __restrict__ partial4,
                                             float* __restrict__ mask) {
    __shared__ float rs[H];
    const int b = blockIdx.x;
    const int t = threadIdx.x;  // 0..63

    if (t < HW4) {
        f32x4 s = {0.f, 0.f, 0.f, 0.f};
        #pragma unroll
        for (int ch = 0; ch < CHUNKS; ++ch) {  // fixed order: deterministic
            const f32x4 v = partial4[(size_t)(b * CHUNKS + ch) * HW4 + t];
            s += v;
        }
        float m = fmaxf(fmaxf(s.x, s.y), fmaxf(s.z, s.w));
        m = fmaxf(m, __shfl_xor(m, 1));  // combine the two halves of row t>>1
        if ((t & 1) == 0) rs[t >> 1] = m;
    }
    __syncthreads();

    if (t < H) {
        const float my = rs[t];
        int cnt = 0;
        #pragma unroll
        for (int h = 0; h < H; ++h) {
            const float o = rs[h];
            if (o > my || (o == my && h > t)) ++cnt;
        }
        mask[b * H + t] = (cnt < RH) ? 0.0f : 1.0f;
    }
}

// ---------------------------------------------------------------------------
// Kernel 3: out = x * mask[b,h], float4 in, NONTEMPORAL float4 out (out is
// never re-read; keep it from write-allocating in L2/L3 and evicting x).
// x re-read hits the Infinity Cache (100.7 MB < 256 MiB, just streamed by
// k_ss). Each h-row is exactly 2 float4s, so h = (idx4 >> 1) % H.
// ---------------------------------------------------------------------------
__global__ __launch_bounds__(256) void k_apply(const f32x4* __restrict__ x4,
                                               const float* __restrict__ mask,
                                               f32x4* __restrict__ out4) {
    const int b = blockIdx.y;
    const int idx4 = blockIdx.x * 256 + threadIdx.x;  // float4 idx in batch
    const int h = (idx4 >> 1) % H;
    const float m = mask[b * H + h];
    const size_t e = (size_t)b * CHW4 + idx4;
    const f32x4 v = x4[e];
    __builtin_nontemporal_store(v * m, (f32x4*)(out4 + e));
}

// ---------------------------------------------------------------------------
extern "C" void kernel_launch(void* const* d_in, const int* in_sizes, int n_in,
                              void* d_out, int out_size, void* d_ws, size_t ws_size,
                              hipStream_t stream) {
    const f32x4* x4 = (const f32x4*)d_in[0];
    f32x4* out4 = (f32x4*)d_out;
    f32x4* partial4 = (f32x4*)d_ws;                         // B*CHUNKS*HW floats (768 KB)
    float* mask = (float*)d_ws + (size_t)B * CHUNKS * HW;   // B*H floats

    k_ss<<<B * CHUNKS, 192, 0, stream>>>(x4, partial4);
    k_mask<<<B, 64, 0, stream>>>(partial4, mask);
    k_apply<<<dim3(CHW4 / 256, B), 256, 0, stream>>>(x4, mask, out4);
}